// Round 1
// baseline (512.599 us; speedup 1.0000x reference)
//
#include <hip/hip_runtime.h>
#include <math.h>

// Problem constants (fixed by reference file)
constexpr int Nn   = 50000;
constexpr int Ee   = 400000;
constexpr int FIN  = 256;
constexpr int FHID = 192;
constexpr int FOUT = 128;

// ---------------- preprocessing kernels ----------------

__global__ void init_cnt_k(int* cnt, int n) {
    int i = blockIdx.x * blockDim.x + threadIdx.x;
    if (i < n) cnt[i] = 0;
}

// Decide whether edge_index is int64 (jax x64) or int32 (default jax / harness cast).
// If data is really int32 pairs, reading as int64 gives values >= 2^32 almost surely.
__global__ void detect_k(const long long* p, int n, int* flag) {
    if (threadIdx.x == 0 && blockIdx.x == 0) {
        int ok = 1;
        for (int i = 0; i < 16; i++) {
            long long v = p[i];
            if (v < 0 || v >= n) ok = 0;
        }
        *flag = ok;
    }
}

__global__ void conv_k(const void* edge, const int* flag, int* srcI, int* dstI,
                       int* cnt, int ne) {
    int e = blockIdx.x * blockDim.x + threadIdx.x;
    if (e >= ne) return;
    int s, d;
    if (*flag) {
        const long long* p = (const long long*)edge;
        s = (int)p[e];
        d = (int)p[ne + e];
    } else {
        const int* p = (const int*)edge;
        s = p[e];
        d = p[ne + e];
    }
    srcI[e] = s;
    dstI[e] = d;
    atomicAdd(&cnt[d], 1);
}

__global__ void dinv_k(const int* cnt, float* dinv, int n) {
    int i = blockIdx.x * blockDim.x + threadIdx.x;
    if (i < n) dinv[i] = 1.0f / sqrtf((float)(cnt[i] + 1));  // +1 = self loop
}

// Exclusive scan of cnt -> rowptr, 1024-element chunks (256 thr x 4)
__global__ __launch_bounds__(256) void scan1_k(const int* cnt, int n, int* rowptr,
                                               int* blockSum) {
    __shared__ int sm[256];
    int b = blockIdx.x, tid = threadIdx.x;
    int gbase = b * 1024 + tid * 4;
    int v[4];
#pragma unroll
    for (int j = 0; j < 4; j++) v[j] = (gbase + j < n) ? cnt[gbase + j] : 0;
    int tsum = v[0] + v[1] + v[2] + v[3];
    sm[tid] = tsum;
    __syncthreads();
    for (int off = 1; off < 256; off <<= 1) {
        int t = (tid >= off) ? sm[tid - off] : 0;
        __syncthreads();
        sm[tid] += t;
        __syncthreads();
    }
    int excl = sm[tid] - tsum;
#pragma unroll
    for (int j = 0; j < 4; j++) {
        if (gbase + j < n) rowptr[gbase + j] = excl;
        excl += v[j];
    }
    if (tid == 255) blockSum[b] = sm[255];
}

__global__ void scan2_k(const int* blockSum, int nb, int* blockOff) {
    if (threadIdx.x == 0 && blockIdx.x == 0) {
        int run = 0;
        for (int b = 0; b < nb; b++) { blockOff[b] = run; run += blockSum[b]; }
        blockOff[nb] = run;
    }
}

__global__ void scan3_k(int* rowptr, const int* blockOff, int* cursor, int n, int nb) {
    int i = blockIdx.x * blockDim.x + threadIdx.x;
    if (i < n) {
        int r = rowptr[i] + blockOff[i >> 10];
        rowptr[i] = r;
        cursor[i] = r;
    }
    if (i == 0) rowptr[n] = blockOff[nb];
}

// Sort edges by dst into CSR slots; precompute norm = dinv[src]*dinv[dst]
__global__ void place_k(const int* srcI, const int* dstI, const float* dinv,
                        int* cursor, int* esrc, float* enorm, int ne) {
    int e = blockIdx.x * blockDim.x + threadIdx.x;
    if (e >= ne) return;
    int s = srcI[e], d = dstI[e];
    int pos = atomicAdd(&cursor[d], 1);
    esrc[pos] = s;
    enorm[pos] = dinv[s] * dinv[d];
}

// ---------------- GEMM: out[M,F] = act(in)+b  @ W[K,F] ----------------
// MODE 0: identity input.  MODE 1: relu(in + bin) applied on load.
template <int K, int F, int MODE>
__global__ __launch_bounds__(256) void gemm_k(const float* __restrict__ in,
                                              const float* __restrict__ W,
                                              const float* __restrict__ bin,
                                              float* __restrict__ out, int M) {
    constexpr int BM = 64, BK = 32;
    constexpr int TN = F / 16;      // 12 (F=192) or 8 (F=128)
    constexpr int AP = BK + 4;      // 36: keeps float4 rows 16B-aligned, pads banks
    constexpr int WP = F + 4;       // 196 / 132, both 16B-aligned rows
    __shared__ float As[BM][AP];
    __shared__ float Ws[BK][WP];
    const int tid = threadIdx.x;
    const int tx = tid & 15, ty = tid >> 4;
    const int row0 = blockIdx.x * BM;

    float acc[4][TN];
#pragma unroll
    for (int i = 0; i < 4; i++)
#pragma unroll
        for (int j = 0; j < TN; j++) acc[i][j] = 0.f;

    for (int k0 = 0; k0 < K; k0 += BK) {
        // stage A tile (64 x 32), activation fused on load
#pragma unroll
        for (int p = 0; p < 2; p++) {
            int q = tid + 256 * p;
            int row = q >> 3;           // 0..63
            int kk = (q & 7) << 2;      // 0,4,..,28
            int grow = row0 + row;
            float4 v;
            if (grow < M) {
                v = *(const float4*)(in + (size_t)grow * K + k0 + kk);
                if constexpr (MODE == 1) {
                    float4 bb = *(const float4*)(bin + k0 + kk);
                    v.x = fmaxf(v.x + bb.x, 0.f);
                    v.y = fmaxf(v.y + bb.y, 0.f);
                    v.z = fmaxf(v.z + bb.z, 0.f);
                    v.w = fmaxf(v.w + bb.w, 0.f);
                }
            } else {
                v = make_float4(0.f, 0.f, 0.f, 0.f);
            }
            *(float4*)&As[row][kk] = v;
        }
        // stage W tile (32 x F)
        constexpr int WQ = BK * F / 4 / 256;  // 6 or 4 float4 per thread
#pragma unroll
        for (int p = 0; p < WQ; p++) {
            int q = tid + 256 * p;
            int L = q << 2;
            int k = L / F;
            int c = L - k * F;
            float4 v = *(const float4*)(W + (size_t)(k0 + k) * F + c);
            *(float4*)&Ws[k][c] = v;
        }
        __syncthreads();
#pragma unroll 4
        for (int k = 0; k < BK; k++) {
            float a[4];
#pragma unroll
            for (int i = 0; i < 4; i++) a[i] = As[ty * 4 + i][k];
            float w[TN];
#pragma unroll
            for (int m = 0; m < TN / 4; m++)
                *(float4*)&w[m * 4] = *(const float4*)&Ws[k][tx * TN + m * 4];
#pragma unroll
            for (int i = 0; i < 4; i++)
#pragma unroll
                for (int j = 0; j < TN; j++)
                    acc[i][j] = fmaf(a[i], w[j], acc[i][j]);
        }
        __syncthreads();
    }
#pragma unroll
    for (int i = 0; i < 4; i++) {
        int grow = row0 + ty * 4 + i;
        if (grow < M) {
#pragma unroll
            for (int m = 0; m < TN / 4; m++) {
                float4 v = make_float4(acc[i][m * 4], acc[i][m * 4 + 1],
                                       acc[i][m * 4 + 2], acc[i][m * 4 + 3]);
                *(float4*)(out + (size_t)grow * F + tx * TN + m * 4) = v;
            }
        }
    }
}

// ---------------- pull aggregation: agg[i] = dinv[i]^2*h[i] + sum_e norm*h[src] ----
template <int F>
__global__ void agg_k(const float* __restrict__ h, const float* __restrict__ dinv,
                      const int* __restrict__ rowptr, const int* __restrict__ esrc,
                      const float* __restrict__ enorm, float* __restrict__ out, int n) {
    constexpr int FV = F / 64;  // 3 (F=192) or 2 (F=128)
    int wid = (blockIdx.x * blockDim.x + threadIdx.x) >> 6;
    int lane = threadIdx.x & 63;
    if (wid >= n) return;
    int i = wid;
    float di = dinv[i];
    const float* hrow = h + (size_t)i * F;
    float acc[FV];
#pragma unroll
    for (int j = 0; j < FV; j++) acc[j] = di * di * hrow[lane + 64 * j];
    int e0 = rowptr[i], e1 = rowptr[i + 1];
    for (int e = e0; e < e1; e++) {
        int s = esrc[e];
        float w = enorm[e];
        const float* hs = h + (size_t)s * F;
#pragma unroll
        for (int j = 0; j < FV; j++) acc[j] += w * hs[lane + 64 * j];
    }
    float* orow = out + (size_t)i * F;
#pragma unroll
    for (int j = 0; j < FV; j++) orow[lane + 64 * j] = acc[j];
}

// ---------------- epilogue: sigmoid + threshold ----------------
__global__ void final_k(const float* __restrict__ agg, const float* __restrict__ b3,
                        float* __restrict__ outh, float* __restrict__ outc, int total4) {
    int idx = blockIdx.x * blockDim.x + threadIdx.x;
    if (idx >= total4) return;
    int c4 = idx & 31;  // (idx*4) % 128 / 4
    float4 v = ((const float4*)agg)[idx];
    float4 b = ((const float4*)b3)[c4];
    float4 s;
    s.x = 1.f / (1.f + expf(-(v.x + b.x)));
    s.y = 1.f / (1.f + expf(-(v.y + b.y)));
    s.z = 1.f / (1.f + expf(-(v.z + b.z)));
    s.w = 1.f / (1.f + expf(-(v.w + b.w)));
    ((float4*)outh)[idx] = s;
    float4 t;
    t.x = s.x >= 0.5f ? 1.f : 0.f;
    t.y = s.y >= 0.5f ? 1.f : 0.f;
    t.z = s.z >= 0.5f ? 1.f : 0.f;
    t.w = s.w >= 0.5f ? 1.f : 0.f;
    ((float4*)outc)[idx] = t;
}

// ---------------- launch ----------------
extern "C" void kernel_launch(void* const* d_in, const int* in_sizes, int n_in,
                              void* d_out, int out_size, void* d_ws, size_t ws_size,
                              hipStream_t stream) {
    const float* x  = (const float*)d_in[0];
    const void*  ei = d_in[1];
    const float* W1 = (const float*)d_in[2];
    const float* b1 = (const float*)d_in[3];
    const float* W2 = (const float*)d_in[4];
    const float* b2 = (const float*)d_in[5];
    const float* W3 = (const float*)d_in[6];
    const float* b3 = (const float*)d_in[7];
    float* out = (float*)d_out;

    char* w = (char*)d_ws;
    size_t off = 0;
    auto alloc = [&](size_t bytes) -> void* {
        off = (off + 255) & ~(size_t)255;
        void* p = w + off;
        off += bytes;
        return p;
    };
    float* bufA   = (float*)alloc((size_t)Nn * FHID * 4);  // h_raw
    float* bufB   = (float*)alloc((size_t)Nn * FHID * 4);  // agg
    int*   srcI   = (int*)alloc((size_t)Ee * 4);
    int*   dstI   = (int*)alloc((size_t)Ee * 4);
    int*   esrc   = (int*)alloc((size_t)Ee * 4);
    float* enorm  = (float*)alloc((size_t)Ee * 4);
    int*   cnt    = (int*)alloc((size_t)Nn * 4);
    float* dinv   = (float*)alloc((size_t)Nn * 4);
    int*   rowptr = (int*)alloc((size_t)(Nn + 1) * 4);
    int*   cursor = (int*)alloc((size_t)Nn * 4);
    int*   blockSum = (int*)alloc(64 * 4);
    int*   blockOff = (int*)alloc(65 * 4);
    int*   flag   = (int*)alloc(4);

    const int NB = (Nn + 1023) / 1024;  // 49
    const int gN = (Nn + 255) / 256;    // 196
    const int gE = (Ee + 255) / 256;    // 1563

    init_cnt_k<<<gN, 256, 0, stream>>>(cnt, Nn);
    detect_k<<<1, 64, 0, stream>>>((const long long*)ei, Nn, flag);
    conv_k<<<gE, 256, 0, stream>>>(ei, flag, srcI, dstI, cnt, Ee);
    dinv_k<<<gN, 256, 0, stream>>>(cnt, dinv, Nn);
    scan1_k<<<NB, 256, 0, stream>>>(cnt, Nn, rowptr, blockSum);
    scan2_k<<<1, 64, 0, stream>>>(blockSum, NB, blockOff);
    scan3_k<<<gN, 256, 0, stream>>>(rowptr, blockOff, cursor, Nn, NB);
    place_k<<<gE, 256, 0, stream>>>(srcI, dstI, dinv, cursor, esrc, enorm, Ee);

    const int gM = (Nn + 63) / 64;             // 782
    const int gAgg = (Nn * 64 + 255) / 256;    // 12500

    // layer 1: x @ W1 -> bufA ; aggregate -> bufB
    gemm_k<FIN, FHID, 0><<<gM, 256, 0, stream>>>(x, W1, b1, bufA, Nn);
    agg_k<FHID><<<gAgg, 256, 0, stream>>>(bufA, dinv, rowptr, esrc, enorm, bufB, Nn);
    // layer 2: relu(bufB+b1) @ W2 -> bufA ; aggregate -> bufB
    gemm_k<FHID, FHID, 1><<<gM, 256, 0, stream>>>(bufB, W2, b1, bufA, Nn);
    agg_k<FHID><<<gAgg, 256, 0, stream>>>(bufA, dinv, rowptr, esrc, enorm, bufB, Nn);
    // layer 3: relu(bufB+b2) @ W3 -> bufA ; aggregate -> bufB
    gemm_k<FHID, FOUT, 1><<<gM, 256, 0, stream>>>(bufB, W3, b2, bufA, Nn);
    agg_k<FOUT><<<gAgg, 256, 0, stream>>>(bufA, dinv, rowptr, esrc, enorm, bufB, Nn);
    // epilogue: sigmoid + threshold -> d_out (h then h_clone)
    const int total4 = Nn * FOUT / 4;  // 1.6M
    final_k<<<(total4 + 255) / 256, 256, 0, stream>>>(bufB, b3, out,
                                                      out + (size_t)Nn * FOUT, total4);
}

// Round 3
// 495.887 us; speedup vs baseline: 1.0337x; 1.0337x over previous
//
#include <hip/hip_runtime.h>
#include <math.h>

// Problem constants (fixed by reference file)
constexpr int Nn   = 50000;
constexpr int Ee   = 400000;
constexpr int FIN  = 256;
constexpr int FHID = 192;
constexpr int FOUT = 128;

typedef float    f32x4 __attribute__((ext_vector_type(4)));
typedef _Float16 f16x8 __attribute__((ext_vector_type(8)));

__device__ inline f32x4 mfma16(f16x8 a, f16x8 b, f32x4 c) {
    return __builtin_amdgcn_mfma_f32_16x16x32_f16(a, b, c, 0, 0, 0);
}

// ---------------- preprocessing kernels ----------------

__global__ void init_cnt_k(int* cnt, int n) {
    int i = blockIdx.x * blockDim.x + threadIdx.x;
    if (i < n) cnt[i] = 0;
}

// int64 vs int32 edge_index detection (int32 pairs read as int64 are >= 2^32 a.s.)
__global__ void detect_k(const long long* p, int n, int* flag) {
    if (threadIdx.x == 0 && blockIdx.x == 0) {
        int ok = 1;
        for (int i = 0; i < 16; i++) {
            long long v = p[i];
            if (v < 0 || v >= n) ok = 0;
        }
        *flag = ok;
    }
}

__global__ void conv_k(const void* edge, const int* flag, int* srcI, int* dstI,
                       int* cnt, int ne) {
    int e = blockIdx.x * blockDim.x + threadIdx.x;
    if (e >= ne) return;
    int s, d;
    if (*flag) {
        const long long* p = (const long long*)edge;
        s = (int)p[e];
        d = (int)p[ne + e];
    } else {
        const int* p = (const int*)edge;
        s = p[e];
        d = p[ne + e];
    }
    srcI[e] = s;
    dstI[e] = d;
    atomicAdd(&cnt[d], 1);
}

__global__ void dinv_k(const int* cnt, float* dinv, int n) {
    int i = blockIdx.x * blockDim.x + threadIdx.x;
    if (i < n) dinv[i] = 1.0f / sqrtf((float)(cnt[i] + 1));  // +1 = self loop
}

__global__ __launch_bounds__(256) void scan1_k(const int* cnt, int n, int* rowptr,
                                               int* blockSum) {
    __shared__ int sm[256];
    int b = blockIdx.x, tid = threadIdx.x;
    int gbase = b * 1024 + tid * 4;
    int v[4];
#pragma unroll
    for (int j = 0; j < 4; j++) v[j] = (gbase + j < n) ? cnt[gbase + j] : 0;
    int tsum = v[0] + v[1] + v[2] + v[3];
    sm[tid] = tsum;
    __syncthreads();
    for (int off = 1; off < 256; off <<= 1) {
        int t = (tid >= off) ? sm[tid - off] : 0;
        __syncthreads();
        sm[tid] += t;
        __syncthreads();
    }
    int excl = sm[tid] - tsum;
#pragma unroll
    for (int j = 0; j < 4; j++) {
        if (gbase + j < n) rowptr[gbase + j] = excl;
        excl += v[j];
    }
    if (tid == 255) blockSum[b] = sm[255];
}

__global__ void scan2_k(const int* blockSum, int nb, int* blockOff) {
    if (threadIdx.x == 0 && blockIdx.x == 0) {
        int run = 0;
        for (int b = 0; b < nb; b++) { blockOff[b] = run; run += blockSum[b]; }
        blockOff[nb] = run;
    }
}

__global__ void scan3_k(int* rowptr, const int* blockOff, int* cursor, int n, int nb) {
    int i = blockIdx.x * blockDim.x + threadIdx.x;
    if (i < n) {
        int r = rowptr[i] + blockOff[i >> 10];
        rowptr[i] = r;
        cursor[i] = r;
    }
    if (i == 0) rowptr[n] = blockOff[nb];
}

__global__ void place_k(const int* srcI, const int* dstI, const float* dinv,
                        int* cursor, int* esrc, float* enorm, int ne) {
    int e = blockIdx.x * blockDim.x + threadIdx.x;
    if (e >= ne) return;
    int s = srcI[e], d = dstI[e];
    int pos = atomicAdd(&cursor[d], 1);
    esrc[pos] = s;
    enorm[pos] = dinv[s] * dinv[d];
}

// ---------------- weight split: W[K][F] fp32 -> Wt_hi/lo [F][K] fp16 ----------------
__global__ void split_w_k(const float* __restrict__ W, _Float16* __restrict__ wh,
                          _Float16* __restrict__ wl, int K, int F) {
    int idx = blockIdx.x * blockDim.x + threadIdx.x;
    if (idx >= K * F) return;
    int k = idx / F, f = idx - k * F;
    float w = W[idx];
    _Float16 h = (_Float16)w;
    float d = w - (float)h;
    wh[(size_t)f * K + k] = h;
    wl[(size_t)f * K + k] = (_Float16)(d * 4096.f);
}

// ---------------- MFMA GEMM: out[M,F] = A @ W  (fp16x2 split emulation) --------
// MODE 0: A = fp32 inF, split in-register.  MODE 2: A = pre-split planes inH/inL.
// Wave tile 32x(NR*16); block = 4 waves stacked in rows -> 128 x (NR*16).
template <int K, int F, int NR, int MODE>
__global__ __launch_bounds__(256) void gemm_mfma(
    const float* __restrict__ inF, const _Float16* __restrict__ inH,
    const _Float16* __restrict__ inL, const _Float16* __restrict__ whi,
    const _Float16* __restrict__ wlo, float* __restrict__ out, int M) {
    const int tid  = threadIdx.x;
    const int wid  = tid >> 6;
    const int lane = tid & 63;
    const int l15  = lane & 15;
    const int l4   = lane >> 4;
    const int rb   = blockIdx.x * 128 + wid * 32;
    const int cb   = blockIdx.y * (NR * 16);

    f32x4 accH[2][NR], accL[2][NR];
#pragma unroll
    for (int mi = 0; mi < 2; mi++)
#pragma unroll
        for (int ni = 0; ni < NR; ni++)
#pragma unroll
            for (int r = 0; r < 4; r++) { accH[mi][ni][r] = 0.f; accL[mi][ni][r] = 0.f; }

    for (int k0 = 0; k0 < K; k0 += 32) {
        const int kk = k0 + l4 * 8;
        f16x8 ah[2], al[2];
#pragma unroll
        for (int mi = 0; mi < 2; mi++) {
            const int row = rb + mi * 16 + l15;
            if constexpr (MODE == 0) {
                if (row < M) {
                    const float* p = inF + (size_t)row * K + kk;
                    float4 f0 = *(const float4*)p;
                    float4 f1 = *(const float4*)(p + 4);
                    float v[8] = {f0.x, f0.y, f0.z, f0.w, f1.x, f1.y, f1.z, f1.w};
#pragma unroll
                    for (int j = 0; j < 8; j++) {
                        _Float16 h = (_Float16)v[j];
                        float d = v[j] - (float)h;
                        ah[mi][j] = h;
                        al[mi][j] = (_Float16)(d * 4096.f);
                    }
                } else {
#pragma unroll
                    for (int j = 0; j < 8; j++) { ah[mi][j] = (_Float16)0.f; al[mi][j] = (_Float16)0.f; }
                }
            } else {
                if (row < M) {
                    ah[mi] = *(const f16x8*)(inH + (size_t)row * K + kk);
                    al[mi] = *(const f16x8*)(inL + (size_t)row * K + kk);
                } else {
#pragma unroll
                    for (int j = 0; j < 8; j++) { ah[mi][j] = (_Float16)0.f; al[mi][j] = (_Float16)0.f; }
                }
            }
        }
#pragma unroll
        for (int ni = 0; ni < NR; ni++) {
            const int col = cb + ni * 16 + l15;
            f16x8 bh = *(const f16x8*)(whi + (size_t)col * K + kk);
            f16x8 bl = *(const f16x8*)(wlo + (size_t)col * K + kk);
#pragma unroll
            for (int mi = 0; mi < 2; mi++) {
                accH[mi][ni] = mfma16(ah[mi], bh, accH[mi][ni]);
                accL[mi][ni] = mfma16(ah[mi], bl, accL[mi][ni]);
                accL[mi][ni] = mfma16(al[mi], bh, accL[mi][ni]);
            }
        }
    }
    // epilogue: C frag layout col=lane&15, row=(lane>>4)*4+r  [verified m89/m91]
#pragma unroll
    for (int mi = 0; mi < 2; mi++)
#pragma unroll
        for (int r = 0; r < 4; r++) {
            const int row = rb + mi * 16 + l4 * 4 + r;
            if (row < M) {
#pragma unroll
                for (int ni = 0; ni < NR; ni++) {
                    const int col = cb + ni * 16 + l15;
                    out[(size_t)row * F + col] =
                        accH[mi][ni][r] + accL[mi][ni][r] * (1.f / 4096.f);
                }
            }
        }
}

// ---------------- pull aggregation ----------------
// acc[i] = dinv[i]^2*h[i] + sum_e norm*h[src]
// WS=1: write act=relu(acc+bias) as fp16x2 split planes (next GEMM's A).
// WS=0: write fp32 (final layer, bias applied in final_k).
template <int F, int WS>
__global__ void agg2_k(const float* __restrict__ h, const float* __restrict__ dinv,
                       const int* __restrict__ rowptr, const int* __restrict__ esrc,
                       const float* __restrict__ enorm, const float* __restrict__ bias,
                       _Float16* __restrict__ ah, _Float16* __restrict__ al,
                       float* __restrict__ outf, int n) {
    constexpr int FV = F / 64;
    int wid = (blockIdx.x * blockDim.x + threadIdx.x) >> 6;
    int lane = threadIdx.x & 63;
    if (wid >= n) return;
    int i = wid;
    float di = dinv[i];
    const float* hrow = h + (size_t)i * F;
    float acc[FV];
#pragma unroll
    for (int j = 0; j < FV; j++) acc[j] = di * di * hrow[lane + 64 * j];
    int e0 = rowptr[i], e1 = rowptr[i + 1];
    for (int e = e0; e < e1; e++) {
        int s = esrc[e];
        float w = enorm[e];
        const float* hs = h + (size_t)s * F;
#pragma unroll
        for (int j = 0; j < FV; j++) acc[j] += w * hs[lane + 64 * j];
    }
#pragma unroll
    for (int j = 0; j < FV; j++) {
        int c = lane + 64 * j;
        if constexpr (WS == 1) {
            float a = fmaxf(acc[j] + bias[c], 0.f);
            _Float16 hh = (_Float16)a;
            float d = a - (float)hh;
            ah[(size_t)i * F + c] = hh;
            al[(size_t)i * F + c] = (_Float16)(d * 4096.f);
        } else {
            outf[(size_t)i * F + c] = acc[j];
        }
    }
}

// ---------------- epilogue: sigmoid + threshold ----------------
__global__ void final_k(const float* __restrict__ agg, const float* __restrict__ b3,
                        float* __restrict__ outh, float* __restrict__ outc, int total4) {
    int idx = blockIdx.x * blockDim.x + threadIdx.x;
    if (idx >= total4) return;
    int c4 = idx & 31;
    float4 v = ((const float4*)agg)[idx];
    float4 b = ((const float4*)b3)[c4];
    float4 s;
    s.x = 1.f / (1.f + expf(-(v.x + b.x)));
    s.y = 1.f / (1.f + expf(-(v.y + b.y)));
    s.z = 1.f / (1.f + expf(-(v.z + b.z)));
    s.w = 1.f / (1.f + expf(-(v.w + b.w)));
    ((float4*)outh)[idx] = s;
    float4 t;
    t.x = s.x >= 0.5f ? 1.f : 0.f;
    t.y = s.y >= 0.5f ? 1.f : 0.f;
    t.z = s.z >= 0.5f ? 1.f : 0.f;
    t.w = s.w >= 0.5f ? 1.f : 0.f;
    ((float4*)outc)[idx] = t;
}

// ---------------- launch ----------------
extern "C" void kernel_launch(void* const* d_in, const int* in_sizes, int n_in,
                              void* d_out, int out_size, void* d_ws, size_t ws_size,
                              hipStream_t stream) {
    const float* x  = (const float*)d_in[0];
    const void*  ei = d_in[1];
    const float* W1 = (const float*)d_in[2];
    const float* b1 = (const float*)d_in[3];
    const float* W2 = (const float*)d_in[4];
    const float* b2 = (const float*)d_in[5];
    const float* W3 = (const float*)d_in[6];
    const float* b3 = (const float*)d_in[7];
    float* out = (float*)d_out;

    char* w = (char*)d_ws;
    size_t off = 0;
    auto alloc = [&](size_t bytes) -> void* {
        off = (off + 255) & ~(size_t)255;
        void* p = w + off;
        off += bytes;
        return p;
    };
    float*     bufA = (float*)alloc((size_t)Nn * FHID * 4);      // GEMM out (fp32)
    _Float16*  Ph   = (_Float16*)alloc((size_t)Nn * FHID * 2 * 2); // split planes / agg3 f32
    _Float16*  Pl   = Ph + (size_t)Nn * FHID;
    float*     Pf   = (float*)Ph;                                 // aliased: agg3 fp32 out
    int*   srcI   = (int*)alloc((size_t)Ee * 4);
    int*   dstI   = (int*)alloc((size_t)Ee * 4);
    int*   esrc   = (int*)alloc((size_t)Ee * 4);
    float* enorm  = (float*)alloc((size_t)Ee * 4);
    int*   cnt    = (int*)alloc((size_t)Nn * 4);
    float* dinv   = (float*)alloc((size_t)Nn * 4);
    int*   rowptr = (int*)alloc((size_t)(Nn + 1) * 4);
    int*   cursor = (int*)alloc((size_t)Nn * 4);
    int*   blockSum = (int*)alloc(64 * 4);
    int*   blockOff = (int*)alloc(65 * 4);
    int*   flag   = (int*)alloc(4);
    _Float16* w1h = (_Float16*)alloc((size_t)FIN * FHID * 2);
    _Float16* w1l = (_Float16*)alloc((size_t)FIN * FHID * 2);
    _Float16* w2h = (_Float16*)alloc((size_t)FHID * FHID * 2);
    _Float16* w2l = (_Float16*)alloc((size_t)FHID * FHID * 2);
    _Float16* w3h = (_Float16*)alloc((size_t)FHID * FOUT * 2);
    _Float16* w3l = (_Float16*)alloc((size_t)FHID * FOUT * 2);

    const int NB = (Nn + 1023) / 1024;
    const int gN = (Nn + 255) / 256;
    const int gE = (Ee + 255) / 256;

    init_cnt_k<<<gN, 256, 0, stream>>>(cnt, Nn);
    detect_k<<<1, 64, 0, stream>>>((const long long*)ei, Nn, flag);
    conv_k<<<gE, 256, 0, stream>>>(ei, flag, srcI, dstI, cnt, Ee);
    dinv_k<<<gN, 256, 0, stream>>>(cnt, dinv, Nn);
    scan1_k<<<NB, 256, 0, stream>>>(cnt, Nn, rowptr, blockSum);
    scan2_k<<<1, 64, 0, stream>>>(blockSum, NB, blockOff);
    scan3_k<<<gN, 256, 0, stream>>>(rowptr, blockOff, cursor, Nn, NB);
    place_k<<<gE, 256, 0, stream>>>(srcI, dstI, dinv, cursor, esrc, enorm, Ee);

    split_w_k<<<(FIN * FHID + 255) / 256, 256, 0, stream>>>(W1, w1h, w1l, FIN, FHID);
    split_w_k<<<(FHID * FHID + 255) / 256, 256, 0, stream>>>(W2, w2h, w2l, FHID, FHID);
    split_w_k<<<(FHID * FOUT + 255) / 256, 256, 0, stream>>>(W3, w3h, w3l, FHID, FOUT);

    const int gRows = (Nn + 127) / 128;              // 391
    const int gAgg  = (Nn * 64 + 255) / 256;         // 12500

    // layer 1: x @ W1 -> bufA ; aggregate (+b1, relu, split) -> Ph/Pl
    gemm_mfma<FIN, FHID, 6, 0><<<dim3(gRows, 2), 256, 0, stream>>>(
        x, nullptr, nullptr, w1h, w1l, bufA, Nn);
    agg2_k<FHID, 1><<<gAgg, 256, 0, stream>>>(bufA, dinv, rowptr, esrc, enorm,
                                              b1, Ph, Pl, nullptr, Nn);
    // layer 2
    gemm_mfma<FHID, FHID, 6, 2><<<dim3(gRows, 2), 256, 0, stream>>>(
        nullptr, Ph, Pl, w2h, w2l, bufA, Nn);
    agg2_k<FHID, 1><<<gAgg, 256, 0, stream>>>(bufA, dinv, rowptr, esrc, enorm,
                                              b2, Ph, Pl, nullptr, Nn);
    // layer 3
    gemm_mfma<FHID, FOUT, 4, 2><<<dim3(gRows, 2), 256, 0, stream>>>(
        nullptr, Ph, Pl, w3h, w3l, bufA, Nn);
    agg2_k<FOUT, 0><<<gAgg, 256, 0, stream>>>(bufA, dinv, rowptr, esrc, enorm,
                                              nullptr, nullptr, nullptr, Pf, Nn);
    // epilogue
    const int total4 = Nn * FOUT / 4;
    final_k<<<(total4 + 255) / 256, 256, 0, stream>>>(Pf, b3, out,
                                                      out + (size_t)Nn * FOUT, total4);
}

// Round 5
// 460.867 us; speedup vs baseline: 1.1122x; 1.0760x over previous
//
#include <hip/hip_runtime.h>
#include <math.h>

// Problem constants (fixed by reference file)
constexpr int Nn   = 50000;
constexpr int Ee   = 400000;
constexpr int FIN  = 256;
constexpr int FHID = 192;
constexpr int FOUT = 128;

typedef float    f32x4 __attribute__((ext_vector_type(4)));
typedef _Float16 f16x8 __attribute__((ext_vector_type(8)));

__device__ inline f32x4 mfma16(f16x8 a, f16x8 b, f32x4 c) {
    return __builtin_amdgcn_mfma_f32_16x16x32_f16(a, b, c, 0, 0, 0);
}

// ---------------- preprocessing kernels (unchanged from R3 — verified) ---------

__global__ void init_cnt_k(int* cnt, int n) {
    int i = blockIdx.x * blockDim.x + threadIdx.x;
    if (i < n) cnt[i] = 0;
}

__global__ void detect_k(const long long* p, int n, int* flag) {
    if (threadIdx.x == 0 && blockIdx.x == 0) {
        int ok = 1;
        for (int i = 0; i < 16; i++) {
            long long v = p[i];
            if (v < 0 || v >= n) ok = 0;
        }
        *flag = ok;
    }
}

__global__ void conv_k(const void* edge, const int* flag, int* srcI, int* dstI,
                       int* cnt, int ne) {
    int e = blockIdx.x * blockDim.x + threadIdx.x;
    if (e >= ne) return;
    int s, d;
    if (*flag) {
        const long long* p = (const long long*)edge;
        s = (int)p[e];
        d = (int)p[ne + e];
    } else {
        const int* p = (const int*)edge;
        s = p[e];
        d = p[ne + e];
    }
    srcI[e] = s;
    dstI[e] = d;
    atomicAdd(&cnt[d], 1);
}

__global__ void dinv_k(const int* cnt, float* dinv, int n) {
    int i = blockIdx.x * blockDim.x + threadIdx.x;
    if (i < n) dinv[i] = 1.0f / sqrtf((float)(cnt[i] + 1));  // +1 = self loop
}

__global__ __launch_bounds__(256) void scan1_k(const int* cnt, int n, int* rowptr,
                                               int* blockSum) {
    __shared__ int sm[256];
    int b = blockIdx.x, tid = threadIdx.x;
    int gbase = b * 1024 + tid * 4;
    int v[4];
#pragma unroll
    for (int j = 0; j < 4; j++) v[j] = (gbase + j < n) ? cnt[gbase + j] : 0;
    int tsum = v[0] + v[1] + v[2] + v[3];
    sm[tid] = tsum;
    __syncthreads();
    for (int off = 1; off < 256; off <<= 1) {
        int t = (tid >= off) ? sm[tid - off] : 0;
        __syncthreads();
        sm[tid] += t;
        __syncthreads();
    }
    int excl = sm[tid] - tsum;
#pragma unroll
    for (int j = 0; j < 4; j++) {
        if (gbase + j < n) rowptr[gbase + j] = excl;
        excl += v[j];
    }
    if (tid == 255) blockSum[b] = sm[255];
}

__global__ void scan2_k(const int* blockSum, int nb, int* blockOff) {
    if (threadIdx.x == 0 && blockIdx.x == 0) {
        int run = 0;
        for (int b = 0; b < nb; b++) { blockOff[b] = run; run += blockSum[b]; }
        blockOff[nb] = run;
    }
}

__global__ void scan3_k(int* rowptr, const int* blockOff, int* cursor, int n, int nb) {
    int i = blockIdx.x * blockDim.x + threadIdx.x;
    if (i < n) {
        int r = rowptr[i] + blockOff[i >> 10];
        rowptr[i] = r;
        cursor[i] = r;
    }
    if (i == 0) rowptr[n] = blockOff[nb];
}

__global__ void place_k(const int* srcI, const int* dstI, const float* dinv,
                        int* cursor, int* esrc, float* enorm, int ne) {
    int e = blockIdx.x * blockDim.x + threadIdx.x;
    if (e >= ne) return;
    int s = srcI[e], d = dstI[e];
    int pos = atomicAdd(&cursor[d], 1);
    esrc[pos] = s;
    enorm[pos] = dinv[s] * dinv[d];
}

// ---------------- weight split: W[K][F] fp32 -> Wt_hi/lo [F][K] fp16 -----------
__global__ void split_w_k(const float* __restrict__ W, _Float16* __restrict__ wh,
                          _Float16* __restrict__ wl, int K, int F) {
    int idx = blockIdx.x * blockDim.x + threadIdx.x;
    if (idx >= K * F) return;
    int k = idx / F, f = idx - k * F;
    float w = W[idx];
    _Float16 h = (_Float16)w;
    float d = w - (float)h;
    wh[(size_t)f * K + k] = h;
    wl[(size_t)f * K + k] = (_Float16)(d * 4096.f);
}

// ---------------- MFMA GEMM v2: register-double-buffered k-pipeline ------------
// out[M,F] = A @ W via fp16x2-split (3 MFMA per tile). Wave tile 32 x (NR*16),
// block = 4 waves (2 row x 2 col) -> 64 rows x (NR*32) cols, grid.y covers F.
// Two named register sets (S0/S1); k-loop unrolled by 2 so next set's global
// loads are in flight during current set's MFMAs (T14 issue-early pattern).
template <int NR, int MODE>
struct KSet {
    f16x8  bh[NR], bl[NR];
    f16x8  ah[2], al[2];    // MODE 2: pre-split A planes
    float4 ar[2][2];        // MODE 0: raw fp32 A
};

template <int K, int F, int NR, int MODE>
__device__ inline void load_set(KSet<NR, MODE>& S, int kk,
                                const float* __restrict__ inF,
                                const _Float16* __restrict__ inH,
                                const _Float16* __restrict__ inL,
                                const _Float16* __restrict__ whi,
                                const _Float16* __restrict__ wlo,
                                int r0, int r1, int cb, int l15) {
#pragma unroll
    for (int ni = 0; ni < NR; ni++) {
        const size_t boff = (size_t)(cb + ni * 16 + l15) * K + kk;
        S.bh[ni] = *(const f16x8*)(whi + boff);
        S.bl[ni] = *(const f16x8*)(wlo + boff);
    }
    if constexpr (MODE == 0) {
        const float* p0 = inF + (size_t)r0 * K + kk;
        const float* p1 = inF + (size_t)r1 * K + kk;
        S.ar[0][0] = *(const float4*)p0;
        S.ar[0][1] = *(const float4*)(p0 + 4);
        S.ar[1][0] = *(const float4*)p1;
        S.ar[1][1] = *(const float4*)(p1 + 4);
    } else {
        S.ah[0] = *(const f16x8*)(inH + (size_t)r0 * K + kk);
        S.al[0] = *(const f16x8*)(inL + (size_t)r0 * K + kk);
        S.ah[1] = *(const f16x8*)(inH + (size_t)r1 * K + kk);
        S.al[1] = *(const f16x8*)(inL + (size_t)r1 * K + kk);
    }
}

__device__ inline void split8(float4 f0, float4 f1, f16x8& h, f16x8& l) {
    float v[8] = {f0.x, f0.y, f0.z, f0.w, f1.x, f1.y, f1.z, f1.w};
#pragma unroll
    for (int j = 0; j < 8; j++) {
        _Float16 hh = (_Float16)v[j];
        h[j] = hh;
        l[j] = (_Float16)((v[j] - (float)hh) * 4096.f);
    }
}

template <int NR, int MODE>
__device__ inline void consume_set(KSet<NR, MODE>& S, f32x4 (&accH)[2][NR],
                                   f32x4 (&accL)[2][NR]) {
    f16x8 ah[2], al[2];
    if constexpr (MODE == 0) {
        split8(S.ar[0][0], S.ar[0][1], ah[0], al[0]);
        split8(S.ar[1][0], S.ar[1][1], ah[1], al[1]);
    } else {
        ah[0] = S.ah[0]; al[0] = S.al[0];
        ah[1] = S.ah[1]; al[1] = S.al[1];
    }
#pragma unroll
    for (int ni = 0; ni < NR; ni++)
#pragma unroll
        for (int mi = 0; mi < 2; mi++) {
            accH[mi][ni] = mfma16(ah[mi], S.bh[ni], accH[mi][ni]);
            accL[mi][ni] = mfma16(ah[mi], S.bl[ni], accL[mi][ni]);
            accL[mi][ni] = mfma16(al[mi], S.bh[ni], accL[mi][ni]);
        }
}

template <int K, int F, int NR, int MODE>
__global__ __launch_bounds__(256) void gemm_v2(
    const float* __restrict__ inF, const _Float16* __restrict__ inH,
    const _Float16* __restrict__ inL, const _Float16* __restrict__ whi,
    const _Float16* __restrict__ wlo, float* __restrict__ out, int M) {
    const int tid  = threadIdx.x;
    const int lane = tid & 63;
    const int l15  = lane & 15;
    const int l4   = lane >> 4;
    const int wid  = tid >> 6;
    const int wrow = wid >> 1, wcol = wid & 1;
    const int rb   = blockIdx.x * 64 + wrow * 32;
    const int cb   = (blockIdx.y * 2 + wcol) * (NR * 16);
    // clamp OOB rows to M-1: garbage-but-finite, stores are guarded
    const int r0 = min(rb + l15, M - 1);
    const int r1 = min(rb + 16 + l15, M - 1);
    const int kbase = l4 * 8;

    f32x4 accH[2][NR], accL[2][NR];
#pragma unroll
    for (int mi = 0; mi < 2; mi++)
#pragma unroll
        for (int ni = 0; ni < NR; ni++)
#pragma unroll
            for (int r = 0; r < 4; r++) { accH[mi][ni][r] = 0.f; accL[mi][ni][r] = 0.f; }

    KSet<NR, MODE> S0, S1;
    load_set<K, F, NR, MODE>(S0, kbase, inF, inH, inL, whi, wlo, r0, r1, cb, l15);
    for (int k0 = 0; k0 < K; k0 += 64) {
        const int ka = (k0 + 32 < K) ? k0 + 32 : 0;   // last: harmless dummy load
        load_set<K, F, NR, MODE>(S1, ka + kbase, inF, inH, inL, whi, wlo, r0, r1, cb, l15);
        consume_set<NR, MODE>(S0, accH, accL);
        const int kb = (k0 + 64 < K) ? k0 + 64 : 0;
        load_set<K, F, NR, MODE>(S0, kb + kbase, inF, inH, inL, whi, wlo, r0, r1, cb, l15);
        consume_set<NR, MODE>(S1, accH, accL);
    }

    // C frag layout: col=lane&15, row=(lane>>4)*4+r  [verified m89/m91 + R3 pass]
#pragma unroll
    for (int mi = 0; mi < 2; mi++)
#pragma unroll
        for (int r = 0; r < 4; r++) {
            const int row = rb + mi * 16 + l4 * 4 + r;
            if (row < M) {
#pragma unroll
                for (int ni = 0; ni < NR; ni++) {
                    const int col = cb + ni * 16 + l15;
                    out[(size_t)row * F + col] =
                        accH[mi][ni][r] + accL[mi][ni][r] * (1.f / 4096.f);
                }
            }
        }
}

// ---------------- pull aggregation, edge-loop unrolled x4 ----------------------
// acc[i] = dinv[i]^2*h[i] + sum_e norm*h[src]
// WS=1: write act=relu(acc+bias) as fp16x2 split planes (next GEMM's A).
// WS=0: FUSED final layer: h=sigmoid(acc+bias) -> outh; (h>=0.5) -> outc.
template <int F, int WS>
__global__ void agg2_k(const float* __restrict__ h, const float* __restrict__ dinv,
                       const int* __restrict__ rowptr, const int* __restrict__ esrc,
                       const float* __restrict__ enorm, const float* __restrict__ bias,
                       _Float16* __restrict__ ah, _Float16* __restrict__ al,
                       float* __restrict__ outh, float* __restrict__ outc, int n) {
    constexpr int FV = F / 64;
    int i = (blockIdx.x * blockDim.x + threadIdx.x) >> 6;
    int lane = threadIdx.x & 63;
    if (i >= n) return;
    float di = dinv[i];
    const float* hrow = h + (size_t)i * F;
    float acc[FV];
#pragma unroll
    for (int j = 0; j < FV; j++) acc[j] = di * di * hrow[lane + 64 * j];
    const int e1 = rowptr[i + 1];
    int e = rowptr[i];
    for (; e + 4 <= e1; e += 4) {
        int s0 = esrc[e], s1 = esrc[e + 1], s2 = esrc[e + 2], s3 = esrc[e + 3];
        float w0 = enorm[e], w1 = enorm[e + 1], w2 = enorm[e + 2], w3 = enorm[e + 3];
        const float* p0 = h + (size_t)s0 * F;
        const float* p1 = h + (size_t)s1 * F;
        const float* p2 = h + (size_t)s2 * F;
        const float* p3 = h + (size_t)s3 * F;
#pragma unroll
        for (int j = 0; j < FV; j++) {
            int c = lane + 64 * j;
            float v0 = p0[c], v1 = p1[c], v2 = p2[c], v3 = p3[c];
            acc[j] += w0 * v0;
            acc[j] += w1 * v1;
            acc[j] += w2 * v2;
            acc[j] += w3 * v3;
        }
    }
    for (; e < e1; e++) {
        int s = esrc[e];
        float w = enorm[e];
        const float* hs = h + (size_t)s * F;
#pragma unroll
        for (int j = 0; j < FV; j++) acc[j] += w * hs[lane + 64 * j];
    }
#pragma unroll
    for (int j = 0; j < FV; j++) {
        int c = lane + 64 * j;
        if constexpr (WS == 1) {
            float a = fmaxf(acc[j] + bias[c], 0.f);
            _Float16 hh = (_Float16)a;
            float d = a - (float)hh;
            ah[(size_t)i * F + c] = hh;
            al[(size_t)i * F + c] = (_Float16)(d * 4096.f);
        } else {
            float s = 1.f / (1.f + expf(-(acc[j] + bias[c])));
            outh[(size_t)i * F + c] = s;
            outc[(size_t)i * F + c] = (s >= 0.5f) ? 1.f : 0.f;
        }
    }
}

// ---------------- launch ----------------
extern "C" void kernel_launch(void* const* d_in, const int* in_sizes, int n_in,
                              void* d_out, int out_size, void* d_ws, size_t ws_size,
                              hipStream_t stream) {
    const float* x  = (const float*)d_in[0];
    const void*  ei = d_in[1];
    const float* W1 = (const float*)d_in[2];
    const float* b1 = (const float*)d_in[3];
    const float* W2 = (const float*)d_in[4];
    const float* b2 = (const float*)d_in[5];
    const float* W3 = (const float*)d_in[6];
    const float* b3 = (const float*)d_in[7];
    float* out = (float*)d_out;

    char* w = (char*)d_ws;
    size_t off = 0;
    auto alloc = [&](size_t bytes) -> void* {
        off = (off + 255) & ~(size_t)255;
        void* p = w + off;
        off += bytes;
        return p;
    };
    float*     bufA = (float*)alloc((size_t)Nn * FHID * 4);        // GEMM out (fp32)
    _Float16*  Ph   = (_Float16*)alloc((size_t)Nn * FHID * 2);     // split hi plane
    _Float16*  Pl   = (_Float16*)alloc((size_t)Nn * FHID * 2);     // split lo plane
    int*   srcI   = (int*)alloc((size_t)Ee * 4);
    int*   dstI   = (int*)alloc((size_t)Ee * 4);
    int*   esrc   = (int*)alloc((size_t)Ee * 4);
    float* enorm  = (float*)alloc((size_t)Ee * 4);
    int*   cnt    = (int*)alloc((size_t)Nn * 4);
    float* dinv   = (float*)alloc((size_t)Nn * 4);
    int*   rowptr = (int*)alloc((size_t)(Nn + 1) * 4);
    int*   cursor = (int*)alloc((size_t)Nn * 4);
    int*   blockSum = (int*)alloc(64 * 4);
    int*   blockOff = (int*)alloc(65 * 4);
    int*   flag   = (int*)alloc(4);
    _Float16* w1h = (_Float16*)alloc((size_t)FIN * FHID * 2);
    _Float16* w1l = (_Float16*)alloc((size_t)FIN * FHID * 2);
    _Float16* w2h = (_Float16*)alloc((size_t)FHID * FHID * 2);
    _Float16* w2l = (_Float16*)alloc((size_t)FHID * FHID * 2);
    _Float16* w3h = (_Float16*)alloc((size_t)FHID * FOUT * 2);
    _Float16* w3l = (_Float16*)alloc((size_t)FHID * FOUT * 2);

    const int NB = (Nn + 1023) / 1024;
    const int gN = (Nn + 255) / 256;
    const int gE = (Ee + 255) / 256;

    init_cnt_k<<<gN, 256, 0, stream>>>(cnt, Nn);
    detect_k<<<1, 64, 0, stream>>>((const long long*)ei, Nn, flag);
    conv_k<<<gE, 256, 0, stream>>>(ei, flag, srcI, dstI, cnt, Ee);
    dinv_k<<<gN, 256, 0, stream>>>(cnt, dinv, Nn);
    scan1_k<<<NB, 256, 0, stream>>>(cnt, Nn, rowptr, blockSum);
    scan2_k<<<1, 64, 0, stream>>>(blockSum, NB, blockOff);
    scan3_k<<<gN, 256, 0, stream>>>(rowptr, blockOff, cursor, Nn, NB);
    place_k<<<gE, 256, 0, stream>>>(srcI, dstI, dinv, cursor, esrc, enorm, Ee);

    split_w_k<<<(FIN * FHID + 255) / 256, 256, 0, stream>>>(W1, w1h, w1l, FIN, FHID);
    split_w_k<<<(FHID * FHID + 255) / 256, 256, 0, stream>>>(W2, w2h, w2l, FHID, FHID);
    split_w_k<<<(FHID * FOUT + 255) / 256, 256, 0, stream>>>(W3, w3h, w3l, FHID, FOUT);

    const int gRows = (Nn + 63) / 64;                // 782
    const int gAgg  = (Nn * 64 + 255) / 256;         // 12500

    // layer 1: x @ W1 -> bufA ; aggregate (+b1, relu, split) -> Ph/Pl
    gemm_v2<FIN, FHID, 3, 0><<<dim3(gRows, 2), 256, 0, stream>>>(
        x, nullptr, nullptr, w1h, w1l, bufA, Nn);
    agg2_k<FHID, 1><<<gAgg, 256, 0, stream>>>(bufA, dinv, rowptr, esrc, enorm,
                                              b1, Ph, Pl, nullptr, nullptr, Nn);
    // layer 2
    gemm_v2<FHID, FHID, 3, 2><<<dim3(gRows, 2), 256, 0, stream>>>(
        nullptr, Ph, Pl, w2h, w2l, bufA, Nn);
    agg2_k<FHID, 1><<<gAgg, 256, 0, stream>>>(bufA, dinv, rowptr, esrc, enorm,
                                              b2, Ph, Pl, nullptr, nullptr, Nn);
    // layer 3
    gemm_v2<FHID, FOUT, 2, 2><<<dim3(gRows, 2), 256, 0, stream>>>(
        nullptr, Ph, Pl, w3h, w3l, bufA, Nn);
    // agg3 fused with bias+sigmoid+threshold epilogue -> d_out (h, then clone)
    agg2_k<FOUT, 0><<<gAgg, 256, 0, stream>>>(bufA, dinv, rowptr, esrc, enorm,
                                              b3, nullptr, nullptr, out,
                                              out + (size_t)Nn * FOUT, Nn);
}

// Round 8
// 405.511 us; speedup vs baseline: 1.2641x; 1.1365x over previous
//
#include <hip/hip_runtime.h>
#include <math.h>

// Problem constants (fixed by reference file)
constexpr int Nn   = 50000;
constexpr int Ee   = 400000;
constexpr int FIN  = 256;
constexpr int FHID = 192;
constexpr int FOUT = 128;
constexpr int MP   = 50048;   // Nn padded to 64 (782 row-blocks)

typedef float    f32x4 __attribute__((ext_vector_type(4)));
typedef _Float16 f16x8 __attribute__((ext_vector_type(8)));

__device__ inline f32x4 mfma16(f16x8 a, f16x8 b, f32x4 c) {
    return __builtin_amdgcn_mfma_f32_16x16x32_f16(a, b, c, 0, 0, 0);
}

// Fragment-linear packing: for a logical [R][K] fp16 plane, the f16x8 chunk
// holding row r, k in [ks*32+kc*8, +8) lives at chunk index
//   U = (((r>>4)*(K/32) + ks)*4 + kc)*16 + (r&15)
// so a wave's MFMA fragment load (lane = kc*16 + r15) is 64 consecutive
// 16B chunks = one contiguous 1KB burst (fixes R5's 16-line gather).

// ---------------- preprocessing kernels (unchanged — verified R3/R5) -----------

__global__ void init_cnt_k(int* cnt, int n) {
    int i = blockIdx.x * blockDim.x + threadIdx.x;
    if (i < n) cnt[i] = 0;
}

__global__ void detect_k(const long long* p, int n, int* flag) {
    if (threadIdx.x == 0 && blockIdx.x == 0) {
        int ok = 1;
        for (int i = 0; i < 16; i++) {
            long long v = p[i];
            if (v < 0 || v >= n) ok = 0;
        }
        *flag = ok;
    }
}

__global__ void conv_k(const void* edge, const int* flag, int* srcI, int* dstI,
                       int* cnt, int ne) {
    int e = blockIdx.x * blockDim.x + threadIdx.x;
    if (e >= ne) return;
    int s, d;
    if (*flag) {
        const long long* p = (const long long*)edge;
        s = (int)p[e];
        d = (int)p[ne + e];
    } else {
        const int* p = (const int*)edge;
        s = p[e];
        d = p[ne + e];
    }
    srcI[e] = s;
    dstI[e] = d;
    atomicAdd(&cnt[d], 1);
}

__global__ void dinv_k(const int* cnt, float* dinv, int n) {
    int i = blockIdx.x * blockDim.x + threadIdx.x;
    if (i < n) dinv[i] = 1.0f / sqrtf((float)(cnt[i] + 1));  // +1 = self loop
}

__global__ __launch_bounds__(256) void scan1_k(const int* cnt, int n, int* rowptr,
                                               int* blockSum) {
    __shared__ int sm[256];
    int b = blockIdx.x, tid = threadIdx.x;
    int gbase = b * 1024 + tid * 4;
    int v[4];
#pragma unroll
    for (int j = 0; j < 4; j++) v[j] = (gbase + j < n) ? cnt[gbase + j] : 0;
    int tsum = v[0] + v[1] + v[2] + v[3];
    sm[tid] = tsum;
    __syncthreads();
    for (int off = 1; off < 256; off <<= 1) {
        int t = (tid >= off) ? sm[tid - off] : 0;
        __syncthreads();
        sm[tid] += t;
        __syncthreads();
    }
    int excl = sm[tid] - tsum;
#pragma unroll
    for (int j = 0; j < 4; j++) {
        if (gbase + j < n) rowptr[gbase + j] = excl;
        excl += v[j];
    }
    if (tid == 255) blockSum[b] = sm[255];
}

__global__ void scan2_k(const int* blockSum, int nb, int* blockOff) {
    if (threadIdx.x == 0 && blockIdx.x == 0) {
        int run = 0;
        for (int b = 0; b < nb; b++) { blockOff[b] = run; run += blockSum[b]; }
        blockOff[nb] = run;
    }
}

__global__ void scan3_k(int* rowptr, const int* blockOff, int* cursor, int n, int nb) {
    int i = blockIdx.x * blockDim.x + threadIdx.x;
    if (i < n) {
        int r = rowptr[i] + blockOff[i >> 10];
        rowptr[i] = r;
        cursor[i] = r;
    }
    if (i == 0) rowptr[n] = blockOff[nb];
}

__global__ void place_k(const int* srcI, const int* dstI, const float* dinv,
                        int* cursor, int* esrc, float* enorm, int ne) {
    int e = blockIdx.x * blockDim.x + threadIdx.x;
    if (e >= ne) return;
    int s = srcI[e], d = dstI[e];
    int pos = atomicAdd(&cursor[d], 1);
    esrc[pos] = s;
    enorm[pos] = dinv[s] * dinv[d];
}

// ------- weight split+pack: W[K][F] fp32 -> fragment-linear hi/lo fp16 planes --
__global__ void split_w_pack(const float* __restrict__ W, _Float16* __restrict__ wh,
                             _Float16* __restrict__ wl, int K, int F) {
    int idx = blockIdx.x * blockDim.x + threadIdx.x;
    if (idx >= K * F) return;
    int k = idx / F, f = idx - k * F;
    float w = W[idx];
    _Float16 h = (_Float16)w;
    float d = w - (float)h;
    int U = (((f >> 4) * (K >> 5) + (k >> 5)) * 4 + ((k >> 3) & 3)) * 16 + (f & 15);
    size_t off = (size_t)U * 8 + (k & 7);
    wh[off] = h;
    wl[off] = (_Float16)(d * 4096.f);
}

// ---------------- MFMA GEMM v3: packed-operand register pipeline ---------------
// out[M,F] = A @ W via fp16x2-split (3 MFMA/tile). Wave tile 32 x (NR*16),
// block = 4 waves (2 row x 2 col); every fragment load = 1KB contiguous burst.
// MODE 0: A = raw fp32 (layer 1, split in-register). MODE 2: A = packed planes.
__device__ inline void split8(float4 f0, float4 f1, f16x8& h, f16x8& l) {
    float v[8] = {f0.x, f0.y, f0.z, f0.w, f1.x, f1.y, f1.z, f1.w};
#pragma unroll
    for (int j = 0; j < 8; j++) {
        _Float16 hh = (_Float16)v[j];
        h[j] = hh;
        l[j] = (_Float16)((v[j] - (float)hh) * 4096.f);
    }
}

template <int NR, int MODE>
struct Set3 {
    f16x8  bh[NR], bl[NR];
    f16x8  ah[2], al[2];    // MODE 2
    float4 ar[2][2];        // MODE 0
};

template <int K, int F, int NR, int MODE>
__global__ __launch_bounds__(256) void gemm_v3(
    const float* __restrict__ inF,
    const _Float16* __restrict__ aHp, const _Float16* __restrict__ aLp,
    const _Float16* __restrict__ bHp, const _Float16* __restrict__ bLp,
    float* __restrict__ out, int M) {
    constexpr int KS = K / 32;
    const int tid  = threadIdx.x;
    const int lane = tid & 63;
    const int l15  = lane & 15;
    const int l4   = lane >> 4;
    const int wid  = tid >> 6;
    const int wrow = wid >> 1, wcol = wid & 1;
    const int rb   = blockIdx.x * 64 + wrow * 32;
    const int cb   = (blockIdx.y * 2 + wcol) * (NR * 16);
    const int rblk0 = rb >> 4;
    const int cblk0 = cb >> 4;
    const f16x8* aH = (const f16x8*)aHp;
    const f16x8* aL = (const f16x8*)aLp;
    const f16x8* bH = (const f16x8*)bHp;
    const f16x8* bL = (const f16x8*)bLp;
    // MODE 0 row clamp (garbage-but-finite for pad rows; stores guarded)
    const int r0 = min(rb + l15, M - 1);
    const int r1 = min(rb + 16 + l15, M - 1);

    f32x4 accH[2][NR], accL[2][NR];
#pragma unroll
    for (int mi = 0; mi < 2; mi++)
#pragma unroll
        for (int ni = 0; ni < NR; ni++)
#pragma unroll
            for (int r = 0; r < 4; r++) { accH[mi][ni][r] = 0.f; accL[mi][ni][r] = 0.f; }

    auto load_set = [&](Set3<NR, MODE>& S, int ks) {
#pragma unroll
        for (int ni = 0; ni < NR; ni++) {
            const int b = ((cblk0 + ni) * KS + ks) * 64 + lane;
            S.bh[ni] = bH[b];
            S.bl[ni] = bL[b];
        }
        if constexpr (MODE == 0) {
            const int kk = ks * 32 + l4 * 8;
            const float* p0 = inF + (size_t)r0 * K + kk;
            const float* p1 = inF + (size_t)r1 * K + kk;
            S.ar[0][0] = *(const float4*)p0;
            S.ar[0][1] = *(const float4*)(p0 + 4);
            S.ar[1][0] = *(const float4*)p1;
            S.ar[1][1] = *(const float4*)(p1 + 4);
        } else {
#pragma unroll
            for (int mi = 0; mi < 2; mi++) {
                const int a = ((rblk0 + mi) * KS + ks) * 64 + lane;
                S.ah[mi] = aH[a];
                S.al[mi] = aL[a];
            }
        }
    };
    auto consume_set = [&](Set3<NR, MODE>& S) {
        f16x8 ah[2], al[2];
        if constexpr (MODE == 0) {
            split8(S.ar[0][0], S.ar[0][1], ah[0], al[0]);
            split8(S.ar[1][0], S.ar[1][1], ah[1], al[1]);
        } else {
            ah[0] = S.ah[0]; al[0] = S.al[0];
            ah[1] = S.ah[1]; al[1] = S.al[1];
        }
#pragma unroll
        for (int ni = 0; ni < NR; ni++)
#pragma unroll
            for (int mi = 0; mi < 2; mi++) {
                accH[mi][ni] = mfma16(ah[mi], S.bh[ni], accH[mi][ni]);
                accL[mi][ni] = mfma16(ah[mi], S.bl[ni], accL[mi][ni]);
                accL[mi][ni] = mfma16(al[mi], S.bh[ni], accL[mi][ni]);
            }
    };

    Set3<NR, MODE> S0, S1;
    load_set(S0, 0);
    for (int ks = 0; ks < KS; ks += 2) {
        load_set(S1, ks + 1);
        consume_set(S0);
        load_set(S0, (ks + 2 < KS) ? ks + 2 : 0);   // last: harmless dummy
        consume_set(S1);
    }

    // C frag layout: col=lane&15, row=(lane>>4)*4+r  [verified m89/m91 + R3/R5 pass]
#pragma unroll
    for (int mi = 0; mi < 2; mi++)
#pragma unroll
        for (int r = 0; r < 4; r++) {
            const int row = rb + mi * 16 + l4 * 4 + r;
            if (row < M) {
#pragma unroll
                for (int ni = 0; ni < NR; ni++) {
                    const int col = cb + ni * 16 + l15;
                    out[(size_t)row * F + col] =
                        accH[mi][ni][r] + accL[mi][ni][r] * (1.f / 4096.f);
                }
            }
        }
}

// ---------------- pull aggregation, edge-loop unrolled x4 ----------------------
// acc[i] = dinv[i]^2*h[i] + sum_e norm*h[src]
// WS=1: write act=relu(acc+bias) split fp16x2, PACKED fragment-linear (next A).
// WS=0: FUSED final layer: h=sigmoid(acc+bias) -> outh; (h>=0.5) -> outc.
template <int F, int WS>
__global__ void agg2_k(const float* __restrict__ h, const float* __restrict__ dinv,
                       const int* __restrict__ rowptr, const int* __restrict__ esrc,
                       const float* __restrict__ enorm, const float* __restrict__ bias,
                       _Float16* __restrict__ ah, _Float16* __restrict__ al,
                       float* __restrict__ outh, float* __restrict__ outc, int n) {
    constexpr int FV = F / 64;
    int i = (blockIdx.x * blockDim.x + threadIdx.x) >> 6;
    int lane = threadIdx.x & 63;
    if (i >= n) return;
    float di = dinv[i];
    const float* hrow = h + (size_t)i * F;
    float acc[FV];
#pragma unroll
    for (int j = 0; j < FV; j++) acc[j] = di * di * hrow[lane + 64 * j];
    const int e1 = rowptr[i + 1];
    int e = rowptr[i];
    for (; e + 4 <= e1; e += 4) {
        int s0 = esrc[e], s1 = esrc[e + 1], s2 = esrc[e + 2], s3 = esrc[e + 3];
        float w0 = enorm[e], w1 = enorm[e + 1], w2 = enorm[e + 2], w3 = enorm[e + 3];
        const float* p0 = h + (size_t)s0 * F;
        const float* p1 = h + (size_t)s1 * F;
        const float* p2 = h + (size_t)s2 * F;
        const float* p3 = h + (size_t)s3 * F;
#pragma unroll
        for (int j = 0; j < FV; j++) {
            int c = lane + 64 * j;
            float v0 = p0[c], v1 = p1[c], v2 = p2[c], v3 = p3[c];
            acc[j] += w0 * v0;
            acc[j] += w1 * v1;
            acc[j] += w2 * v2;
            acc[j] += w3 * v3;
        }
    }
    for (; e < e1; e++) {
        int s = esrc[e];
        float w = enorm[e];
        const float* hs = h + (size_t)s * F;
#pragma unroll
        for (int j = 0; j < FV; j++) acc[j] += w * hs[lane + 64 * j];
    }
#pragma unroll
    for (int j = 0; j < FV; j++) {
        int c = lane + 64 * j;
        if constexpr (WS == 1) {
            float a = fmaxf(acc[j] + bias[c], 0.f);
            _Float16 hh = (_Float16)a;
            float d = a - (float)hh;
            // fragment-linear pack for the next GEMM (K_next = F)
            int U = (((i >> 4) * (F >> 5) + (c >> 5)) * 4 + ((c >> 3) & 3)) * 16 + (i & 15);
            size_t off = (size_t)U * 8 + (c & 7);
            ah[off] = hh;
            al[off] = (_Float16)(d * 4096.f);
        } else {
            float s = 1.f / (1.f + expf(-(acc[j] + bias[c])));
            outh[(size_t)i * F + c] = s;
            outc[(size_t)i * F + c] = (s >= 0.5f) ? 1.f : 0.f;
        }
    }
}

// ---------------- launch ----------------
extern "C" void kernel_launch(void* const* d_in, const int* in_sizes, int n_in,
                              void* d_out, int out_size, void* d_ws, size_t ws_size,
                              hipStream_t stream) {
    const float* x  = (const float*)d_in[0];
    const void*  ei = d_in[1];
    const float* W1 = (const float*)d_in[2];
    const float* b1 = (const float*)d_in[3];
    const float* W2 = (const float*)d_in[4];
    const float* b2 = (const float*)d_in[5];
    const float* W3 = (const float*)d_in[6];
    const float* b3 = (const float*)d_in[7];
    float* out = (float*)d_out;

    char* w = (char*)d_ws;
    size_t off = 0;
    auto alloc = [&](size_t bytes) -> void* {
        off = (off + 255) & ~(size_t)255;
        void* p = w + off;
        off += bytes;
        return p;
    };
    float*     bufA = (float*)alloc((size_t)Nn * FHID * 4);        // GEMM out (fp32)
    _Float16*  Ph   = (_Float16*)alloc((size_t)MP * FHID * 2);     // packed hi plane
    _Float16*  Pl   = (_Float16*)alloc((size_t)MP * FHID * 2);     // packed lo plane
    int*   srcI   = (int*)alloc((size_t)Ee * 4);
    int*   dstI   = (int*)alloc((size_t)Ee * 4);
    int*   esrc   = (int*)alloc((size_t)Ee * 4);
    float* enorm  = (float*)alloc((size_t)Ee * 4);
    int*   cnt    = (int*)alloc((size_t)Nn * 4);
    float* dinv   = (float*)alloc((size_t)Nn * 4);
    int*   rowptr = (int*)alloc((size_t)(Nn + 1) * 4);
    int*   cursor = (int*)alloc((size_t)Nn * 4);
    int*   blockSum = (int*)alloc(64 * 4);
    int*   blockOff = (int*)alloc(65 * 4);
    int*   flag   = (int*)alloc(4);
    _Float16* w1h = (_Float16*)alloc((size_t)FIN * FHID * 2);
    _Float16* w1l = (_Float16*)alloc((size_t)FIN * FHID * 2);
    _Float16* w2h = (_Float16*)alloc((size_t)FHID * FHID * 2);
    _Float16* w2l = (_Float16*)alloc((size_t)FHID * FHID * 2);
    _Float16* w3h = (_Float16*)alloc((size_t)FHID * FOUT * 2);
    _Float16* w3l = (_Float16*)alloc((size_t)FHID * FOUT * 2);

    const int NB = (Nn + 1023) / 1024;
    const int gN = (Nn + 255) / 256;
    const int gE = (Ee + 255) / 256;

    init_cnt_k<<<gN, 256, 0, stream>>>(cnt, Nn);
    detect_k<<<1, 64, 0, stream>>>((const long long*)ei, Nn, flag);
    conv_k<<<gE, 256, 0, stream>>>(ei, flag, srcI, dstI, cnt, Ee);
    dinv_k<<<gN, 256, 0, stream>>>(cnt, dinv, Nn);
    scan1_k<<<NB, 256, 0, stream>>>(cnt, Nn, rowptr, blockSum);
    scan2_k<<<1, 64, 0, stream>>>(blockSum, NB, blockOff);
    scan3_k<<<gN, 256, 0, stream>>>(rowptr, blockOff, cursor, Nn, NB);
    place_k<<<gE, 256, 0, stream>>>(srcI, dstI, dinv, cursor, esrc, enorm, Ee);

    split_w_pack<<<(FIN * FHID + 255) / 256, 256, 0, stream>>>(W1, w1h, w1l, FIN, FHID);
    split_w_pack<<<(FHID * FHID + 255) / 256, 256, 0, stream>>>(W2, w2h, w2l, FHID, FHID);
    split_w_pack<<<(FHID * FOUT + 255) / 256, 256, 0, stream>>>(W3, w3h, w3l, FHID, FOUT);

    const int gRows = MP / 64;                       // 782
    const int gAgg  = (Nn * 64 + 255) / 256;         // 12500

    // layer 1: x @ W1 -> bufA ; aggregate (+b1, relu, split+pack) -> Ph/Pl
    gemm_v3<FIN, FHID, 3, 0><<<dim3(gRows, 2), 256, 0, stream>>>(
        x, nullptr, nullptr, w1h, w1l, bufA, Nn);
    agg2_k<FHID, 1><<<gAgg, 256, 0, stream>>>(bufA, dinv, rowptr, esrc, enorm,
                                              b1, Ph, Pl, nullptr, nullptr, Nn);
    // layer 2
    gemm_v3<FHID, FHID, 3, 2><<<dim3(gRows, 2), 256, 0, stream>>>(
        nullptr, Ph, Pl, w2h, w2l, bufA, Nn);
    agg2_k<FHID, 1><<<gAgg, 256, 0, stream>>>(bufA, dinv, rowptr, esrc, enorm,
                                              b2, Ph, Pl, nullptr, nullptr, Nn);
    // layer 3
    gemm_v3<FHID, FOUT, 2, 2><<<dim3(gRows, 2), 256, 0, stream>>>(
        nullptr, Ph, Pl, w3h, w3l, bufA, Nn);
    // agg3 fused with bias+sigmoid+threshold epilogue -> d_out (h, then clone)
    agg2_k<FOUT, 0><<<gAgg, 256, 0, stream>>>(bufA, dinv, rowptr, esrc, enorm,
                                              b3, nullptr, nullptr, out,
                                              out + (size_t)Nn * FOUT, Nn);
}